// Round 1
// baseline (161.179 us; speedup 1.0000x reference)
//
#include <hip/hip_runtime.h>
#include <hip/hip_bf16.h>
#include <stdint.h>

#define T_DIM 4096
#define H_DIM 1024
#define I_DIM 2048
#define E_ACT 2   // static routing: experts 0,1 at weight 0.5

typedef __bf16 bf16x8 __attribute__((ext_vector_type(8)));
typedef float f32x4 __attribute__((ext_vector_type(4)));
typedef unsigned short ushort_t;
typedef unsigned short us4 __attribute__((ext_vector_type(4)));

__device__ __forceinline__ unsigned short f32_to_bf16(float f) {
  unsigned int u = __float_as_uint(f);
  u += 0x7fffu + ((u >> 16) & 1u);   // round-to-nearest-even
  return (unsigned short)(u >> 16);
}

// async global->LDS, 16B per lane. LDS dest is wave-uniform base + lane*16.
__device__ __forceinline__ void gload_lds16(const void* g, void* l) {
  __builtin_amdgcn_global_load_lds(
      (__attribute__((address_space(1))) void*)(uintptr_t)g,
      (__attribute__((address_space(3))) void*)(unsigned int)(uintptr_t)l,
      16, 0, 0);
}

// ---------------- rmsnorm: x[T][H] f32 -> normed bf16 ----------------
__global__ __launch_bounds__(256) void k_rmsnorm(const float* __restrict__ x,
                                                 const float* __restrict__ scale,
                                                 ushort_t* __restrict__ normed) {
  const int row = blockIdx.x, tid = threadIdx.x;
  const float4 v = ((const float4*)(x + (size_t)row * H_DIM))[tid];
  float ss = v.x * v.x + v.y * v.y + v.z * v.z + v.w * v.w;
#pragma unroll
  for (int off = 32; off > 0; off >>= 1) ss += __shfl_xor(ss, off);
  __shared__ float wsum[4];
  if ((tid & 63) == 0) wsum[tid >> 6] = ss;
  __syncthreads();
  const float tot = wsum[0] + wsum[1] + wsum[2] + wsum[3];
  const float inv = rsqrtf(tot * (1.0f / H_DIM) + 1e-5f);
  const float4 sc = ((const float4*)scale)[tid];
  us4 o;
  o.x = f32_to_bf16(v.x * inv * sc.x);
  o.y = f32_to_bf16(v.y * inv * sc.y);
  o.z = f32_to_bf16(v.z * inv * sc.z);
  o.w = f32_to_bf16(v.w * inv * sc.w);
  ((us4*)(normed + (size_t)row * H_DIM))[tid] = o;
}

// ------- transpose+convert: src[R][C] f32 -> dst[C][R] bf16 (per blockIdx.z expert) -------
__global__ __launch_bounds__(256) void k_transpose_cvt(const float* __restrict__ src,
                                                       ushort_t* __restrict__ dst,
                                                       int R, int C) {
  __shared__ float tile[32][33];
  const size_t eoff = (size_t)blockIdx.z * (size_t)R * (size_t)C;
  src += eoff;
  dst += eoff;
  const int x0 = blockIdx.x * 32, y0 = blockIdx.y * 32;
  const int tx = threadIdx.x & 31, ty = threadIdx.x >> 5;
#pragma unroll
  for (int i = 0; i < 4; ++i)
    tile[ty + 8 * i][tx] = src[(size_t)(y0 + ty + 8 * i) * C + x0 + tx];
  __syncthreads();
#pragma unroll
  for (int i = 0; i < 4; ++i)
    dst[(size_t)(x0 + ty + 8 * i) * R + y0 + tx] = f32_to_bf16(tile[tx][ty + 8 * i]);
}

// ---------------- GEMM1 + bias + activation ----------------
// act[e][T][I] = act_fn( normed[T][H] @ W1[e][H][2I] + b1[e] ), pair (i, i+I)
// w1T layout: [e][2I][H] bf16 (B^T form).
__global__ __launch_bounds__(256, 2) void k_gemm1_act(
    const ushort_t* __restrict__ normed, const ushort_t* __restrict__ w1T,
    const float* __restrict__ b1, ushort_t* __restrict__ act) {
  __shared__ __align__(16) ushort_t lds[2][3][128 * 32];
  const int tid = threadIdx.x;
  const int bx = blockIdx.x;  // I/128 = 16
  const int by = blockIdx.y;  // T/128 = 32
  const int e = blockIdx.z;   // 2
  const int brow = by * 128, bcol = bx * 128;
  const int lane = tid & 63, wid = tid >> 6;
  const int wr = wid >> 1, wc = wid & 1;
  const int r16 = lane & 15, kh = lane >> 4;

  const ushort_t* aBase = normed + (size_t)brow * H_DIM;
  const ushort_t* gBase = w1T + ((size_t)e * 2 * I_DIM + bcol) * H_DIM;
  const ushort_t* lBase = w1T + ((size_t)e * 2 * I_DIM + I_DIM + bcol) * H_DIM;

  f32x4 accg[4][4], accl[4][4];
  const f32x4 zero = {0.f, 0.f, 0.f, 0.f};
#pragma unroll
  for (int m = 0; m < 4; ++m)
#pragma unroll
    for (int n = 0; n < 4; ++n) { accg[m][n] = zero; accl[m][n] = zero; }

  auto stage = [&](int buf, int t) {
    const int k0 = t * 32;
#pragma unroll
    for (int tt = 0; tt < 2; ++tt) {
      const int c = tt * 256 + tid;
      const int row = c >> 2;            // 8 bf16 per 16B chunk, 4 chunks per 32-col row
      const int col = (c & 3) << 3;
      const int ldst = (tt * 256 + (tid & ~63)) * 8;  // wave-uniform chunk base (elems)
      gload_lds16(aBase + (size_t)row * H_DIM + k0 + col, &lds[buf][0][ldst]);
      gload_lds16(gBase + (size_t)row * H_DIM + k0 + col, &lds[buf][1][ldst]);
      gload_lds16(lBase + (size_t)row * H_DIM + k0 + col, &lds[buf][2][ldst]);
    }
  };

  const int aoff = (wr * 64 + r16) * 32 + kh * 8;
  const int boff = (wc * 64 + r16) * 32 + kh * 8;
  auto compute = [&](int buf) {
    const ushort_t* As = lds[buf][0];
    const ushort_t* Bg = lds[buf][1];
    const ushort_t* Bl = lds[buf][2];
    bf16x8 af[4], bg[4], bl[4];
#pragma unroll
    for (int m = 0; m < 4; ++m) af[m] = *(const bf16x8*)(As + aoff + m * 512);
#pragma unroll
    for (int n = 0; n < 4; ++n) {
      bg[n] = *(const bf16x8*)(Bg + boff + n * 512);
      bl[n] = *(const bf16x8*)(Bl + boff + n * 512);
    }
#pragma unroll
    for (int m = 0; m < 4; ++m)
#pragma unroll
      for (int n = 0; n < 4; ++n) {
        accg[m][n] = __builtin_amdgcn_mfma_f32_16x16x32_bf16(af[m], bg[n], accg[m][n], 0, 0, 0);
        accl[m][n] = __builtin_amdgcn_mfma_f32_16x16x32_bf16(af[m], bl[n], accl[m][n], 0, 0, 0);
      }
  };

  const int NT = H_DIM / 32;  // 32
  stage(0, 0);
  __syncthreads();
#pragma unroll 1
  for (int t = 0; t < NT; t += 2) {
    stage(1, t + 1);
    compute(0);
    __syncthreads();
    if (t + 2 < NT) stage(0, t + 2);
    compute(1);
    __syncthreads();
  }

  const float* b1e = b1 + (size_t)e * 2 * I_DIM;
#pragma unroll
  for (int m = 0; m < 4; ++m)
#pragma unroll
    for (int n = 0; n < 4; ++n) {
      const int gcol = bcol + wc * 64 + n * 16 + r16;
      const float bgb = b1e[gcol];
      const float blb = b1e[I_DIM + gcol];
#pragma unroll
      for (int rr = 0; rr < 4; ++rr) {
        const int grow = brow + wr * 64 + m * 16 + kh * 4 + rr;
        const float hg = accg[m][n][rr] + bgb;
        const float hl = accl[m][n][rr] + blb;
        const float g = fminf(hg, 7.f);
        const float l = fminf(fmaxf(hl, -7.f), 7.f);
        const float s = 1.f / (1.f + __expf(-1.702f * g));
        const float a = g * s * (l + 1.f);
        act[((size_t)e * T_DIM + grow) * I_DIM + gcol] = f32_to_bf16(a);
      }
    }
}

// ---------------- GEMM2 over both experts + mix + residual ----------------
// out[T][H] = x + 0.5*sum_e( act[e] @ W2[e] + b2[e] );  w2T layout [e][H][I] bf16
__global__ __launch_bounds__(256, 2) void k_gemm2_mix(
    const ushort_t* __restrict__ act, const ushort_t* __restrict__ w2T,
    const float* __restrict__ x, const float* __restrict__ b2,
    float* __restrict__ out) {
  __shared__ __align__(16) ushort_t lds[2][2][128 * 32];
  const int tid = threadIdx.x;
  const int bx = blockIdx.x;  // H/128 = 8
  const int by = blockIdx.y;  // T/128 = 32
  const int brow = by * 128, bcol = bx * 128;
  const int lane = tid & 63, wid = tid >> 6;
  const int wr = wid >> 1, wc = wid & 1;
  const int r16 = lane & 15, kh = lane >> 4;

  f32x4 acc[4][4];
  const f32x4 zero = {0.f, 0.f, 0.f, 0.f};
#pragma unroll
  for (int m = 0; m < 4; ++m)
#pragma unroll
    for (int n = 0; n < 4; ++n) acc[m][n] = zero;

  auto stage = [&](int buf, int t) {
    const int e = t >> 6;            // 64 K-steps per expert
    const int k0 = (t & 63) * 32;
    const ushort_t* aB = act + ((size_t)e * T_DIM + brow) * I_DIM;
    const ushort_t* bB = w2T + ((size_t)e * H_DIM + bcol) * I_DIM;
#pragma unroll
    for (int tt = 0; tt < 2; ++tt) {
      const int c = tt * 256 + tid;
      const int row = c >> 2;
      const int col = (c & 3) << 3;
      const int ldst = (tt * 256 + (tid & ~63)) * 8;
      gload_lds16(aB + (size_t)row * I_DIM + k0 + col, &lds[buf][0][ldst]);
      gload_lds16(bB + (size_t)row * I_DIM + k0 + col, &lds[buf][1][ldst]);
    }
  };

  const int aoff = (wr * 64 + r16) * 32 + kh * 8;
  const int boff = (wc * 64 + r16) * 32 + kh * 8;
  auto compute = [&](int buf) {
    const ushort_t* As = lds[buf][0];
    const ushort_t* Bs = lds[buf][1];
    bf16x8 af[4], bf[4];
#pragma unroll
    for (int m = 0; m < 4; ++m) af[m] = *(const bf16x8*)(As + aoff + m * 512);
#pragma unroll
    for (int n = 0; n < 4; ++n) bf[n] = *(const bf16x8*)(Bs + boff + n * 512);
#pragma unroll
    for (int m = 0; m < 4; ++m)
#pragma unroll
      for (int n = 0; n < 4; ++n)
        acc[m][n] = __builtin_amdgcn_mfma_f32_16x16x32_bf16(af[m], bf[n], acc[m][n], 0, 0, 0);
  };

  const int NT = 2 * I_DIM / 32;  // 128
  stage(0, 0);
  __syncthreads();
#pragma unroll 1
  for (int t = 0; t < NT; t += 2) {
    stage(1, t + 1);
    compute(0);
    __syncthreads();
    if (t + 2 < NT) stage(0, t + 2);
    compute(1);
    __syncthreads();
  }

#pragma unroll
  for (int m = 0; m < 4; ++m)
#pragma unroll
    for (int n = 0; n < 4; ++n) {
      const int gcol = bcol + wc * 64 + n * 16 + r16;
      const float bb = 0.5f * (b2[gcol] + b2[H_DIM + gcol]);
#pragma unroll
      for (int rr = 0; rr < 4; ++rr) {
        const int grow = brow + wr * 64 + m * 16 + kh * 4 + rr;
        out[(size_t)grow * H_DIM + gcol] =
            x[(size_t)grow * H_DIM + gcol] + 0.5f * acc[m][n][rr] + bb;
      }
    }
}

extern "C" void kernel_launch(void* const* d_in, const int* in_sizes, int n_in,
                              void* d_out, int out_size, void* d_ws, size_t ws_size,
                              hipStream_t stream) {
  const float* x = (const float*)d_in[0];
  const float* scale = (const float*)d_in[1];
  // d_in[2]=gate_kernel, d_in[3]=gate_bias: routing is static, logits unused.
  const float* w1 = (const float*)d_in[4];
  const float* b1 = (const float*)d_in[5];
  const float* w2 = (const float*)d_in[6];
  const float* b2 = (const float*)d_in[7];
  float* out = (float*)d_out;

  ushort_t* ws = (ushort_t*)d_ws;
  ushort_t* normed = ws;                                        // [T][H]
  ushort_t* w1T = normed + (size_t)T_DIM * H_DIM;               // [2][2I][H]
  ushort_t* w2T = w1T + (size_t)E_ACT * 2 * I_DIM * H_DIM;      // [2][H][I]
  ushort_t* actb = w2T + (size_t)E_ACT * H_DIM * I_DIM;         // [2][T][I]

  k_rmsnorm<<<dim3(T_DIM), 256, 0, stream>>>(x, scale, normed);
  k_transpose_cvt<<<dim3(2 * I_DIM / 32, H_DIM / 32, E_ACT), 256, 0, stream>>>(
      w1, w1T, H_DIM, 2 * I_DIM);
  k_transpose_cvt<<<dim3(H_DIM / 32, I_DIM / 32, E_ACT), 256, 0, stream>>>(
      w2, w2T, I_DIM, H_DIM);
  k_gemm1_act<<<dim3(I_DIM / 128, T_DIM / 128, E_ACT), 256, 0, stream>>>(
      normed, w1T, b1, actb);
  k_gemm2_mix<<<dim3(H_DIM / 128, T_DIM / 128), 256, 0, stream>>>(
      actb, w2T, x, b2, out);
}